// Round 17
// baseline (328.448 us; speedup 1.0000x reference)
//
#include <hip/hip_runtime.h>
#include <hip/hip_fp16.h>

#define NU 100000
#define NM 50000
#define RM 4      // user-table sub-ranges (movie-dest gather source)
#define RU 2      // movie-table sub-ranges (user-dest gather source)
#define NBLK 256  // partition blocks
#define NBKT 196  // coarse buckets (50000>>8 -> 196, 100000>>9 -> 196)
#define NH (NBKT * NBLK)

typedef __attribute__((ext_vector_type(8))) _Float16 f16x8;
typedef __attribute__((ext_vector_type(4))) float f32x4;

__device__ __forceinline__ unsigned pk2h(float a, float b) {
  return __builtin_bit_cast(unsigned, __floats2half2_rn(a, b));
}
__device__ __forceinline__ __half2 shfl_xor_h2(__half2 v, int m) {
  return __builtin_bit_cast(__half2, __shfl_xor(__builtin_bit_cast(int, v), m));
}
__device__ __forceinline__ __half2 u2h2(unsigned v) {
  return __builtin_bit_cast(__half2, v);
}

// ---------- scan machinery (for the coarse hist matrix only) ----------
__global__ void k_scan_part(const int* __restrict__ cnt, int* __restrict__ off,
                            int* __restrict__ bsum, int n) {
  __shared__ int wsum[4];
  int t = threadIdx.x;
  int base = blockIdx.x * 1024 + t * 4;
  int v0 = (base + 0 < n) ? cnt[base + 0] : 0;
  int v1 = (base + 1 < n) ? cnt[base + 1] : 0;
  int v2 = (base + 2 < n) ? cnt[base + 2] : 0;
  int v3 = (base + 3 < n) ? cnt[base + 3] : 0;
  int s = v0 + v1 + v2 + v3;
  int lane = t & 63;
  int inc = s;
  #pragma unroll
  for (int d = 1; d < 64; d <<= 1) {
    int x = __shfl_up(inc, d);
    if (lane >= d) inc += x;
  }
  int wid = t >> 6;
  if (lane == 63) wsum[wid] = inc;
  __syncthreads();
  int woff = 0;
  for (int i = 0; i < wid; i++) woff += wsum[i];
  int excl = woff + inc - s;
  if (base + 0 < n) off[base + 0] = excl;
  if (base + 1 < n) off[base + 1] = excl + v0;
  if (base + 2 < n) off[base + 2] = excl + v0 + v1;
  if (base + 3 < n) off[base + 3] = excl + v0 + v1 + v2;
  if (t == 255) bsum[blockIdx.x] = woff + inc;
}

__global__ void k_scan_top(int* bsum, int nb) {
  int lane = threadIdx.x;
  int carry = 0;
  for (int base = 0; base < nb; base += 64) {
    int i = base + lane;
    int v = (i < nb) ? bsum[i] : 0;
    int inc = v;
    #pragma unroll
    for (int d = 1; d < 64; d <<= 1) {
      int x = __shfl_up(inc, d);
      if (lane >= d) inc += x;
    }
    if (i < nb) bsum[i] = carry + inc - v;
    carry += __shfl(inc, 63);
  }
}

__global__ void k_scan_add(int* __restrict__ off, const int* __restrict__ bsum,
                           int n, int total) {
  int i = blockIdx.x * blockDim.x + threadIdx.x;
  if (i < n) {
    off[i] = off[i] + bsum[i >> 10];
  } else if (i == n) {
    off[n] = total;
  }
}

// ---------- merged radix-partition build (both CSRs per pass) ----------
__global__ void __launch_bounds__(1024)
k_hist2(const int* __restrict__ esrc, const int* __restrict__ edst,
        int* __restrict__ hmat, int E) {
  __shared__ int hm[NBKT], hu[NBKT];
  int t = threadIdx.x;
  for (int b = t; b < NBKT; b += 1024) { hm[b] = 0; hu[b] = 0; }
  __syncthreads();
  int chunk = (E + NBLK - 1) / NBLK;
  int beg = blockIdx.x * chunk;
  int end = min(beg + chunk, E);
  for (int e = beg + t; e < end; e += 1024) {
    atomicAdd(&hm[edst[e] >> 8], 1);
    atomicAdd(&hu[esrc[e] >> 9], 1);
  }
  __syncthreads();
  for (int b = t; b < NBKT; b += 1024) {
    hmat[b * NBLK + blockIdx.x] = hm[b];
    hmat[NH + b * NBLK + blockIdx.x] = hu[b];
  }
}

// 4B packed records: (lkey << 17) | payload
__global__ void __launch_bounds__(1024)
k_part2(const int* __restrict__ esrc, const int* __restrict__ edst,
        const int* __restrict__ hbase, unsigned* __restrict__ rec_m,
        unsigned* __restrict__ rec_u, int E) {
  __shared__ int cm[NBKT], cu[NBKT];
  int t = threadIdx.x;
  for (int b = t; b < NBKT; b += 1024) {
    cm[b] = hbase[b * NBLK + blockIdx.x];
    cu[b] = hbase[NH + b * NBLK + blockIdx.x] - E;
  }
  __syncthreads();
  int chunk = (E + NBLK - 1) / NBLK;
  int beg = blockIdx.x * chunk;
  int end = min(beg + chunk, E);
  for (int e = beg + t; e < end; e += 1024) {
    int d = edst[e], s = esrc[e];
    unsigned lm = (unsigned)(d & 255) * RM + (unsigned)s / 25000u;
    int pm = atomicAdd(&cm[d >> 8], 1);
    rec_m[pm] = (lm << 17) | (unsigned)s;
    unsigned lu = (unsigned)(s & 511) * RU + (unsigned)d / 25000u;
    int pu = atomicAdd(&cu[s >> 9], 1);
    rec_u[pu] = (lu << 17) | (unsigned)d;
  }
}

// Merged count + LOCAL scan + scatter (see round 14). 1024 threads: the
// in-LDS scan is exactly 1 element/thread (wlen == 1024 for both halves).
__global__ void __launch_bounds__(1024)
k_bcsr(const unsigned* __restrict__ rec_m, const unsigned* __restrict__ rec_u,
       const int* __restrict__ hbase, int* __restrict__ nbr,
       int* __restrict__ nodeoffM, int* __restrict__ nodeoffU, int E) {
  __shared__ int lcnt[1024];
  __shared__ int wsum[16];
  int b = blockIdx.x, t = threadIdx.x;
  bool mv = b < NBKT;
  int bb = mv ? b : b - NBKT;
  const unsigned* rec = mv ? rec_m : rec_u;
  int R = mv ? RM : RU, SH = mv ? 8 : 9, N = mv ? NM : NU;
  int* nodeoff = mv ? nodeoffM : nodeoffU;
  int rs = mv ? hbase[bb * NBLK] : hbase[NH + bb * NBLK] - E;
  int re = mv ? hbase[(bb + 1) * NBLK] : hbase[NH + (bb + 1) * NBLK] - E;
  int nbase = mv ? 0 : E;  // nbr region offset for this half
  int node_lo = bb << SH;
  int node_hi = min(node_lo + (1 << SH), N);
  lcnt[t] = 0;
  __syncthreads();
  for (int r = rs + t; r < re; r += 1024)
    atomicAdd(&lcnt[rec[r] >> 17], 1);
  __syncthreads();
  // block-wide exclusive scan of lcnt (1 elem/thread), rebased to nbase+rs
  int v = lcnt[t];
  int lane = t & 63;
  int inc = v;
  #pragma unroll
  for (int d = 1; d < 64; d <<= 1) {
    int x = __shfl_up(inc, d);
    if (lane >= d) inc += x;
  }
  int wid = t >> 6;
  if (lane == 63) wsum[wid] = inc;
  __syncthreads();
  int woff = 0;
  for (int k = 0; k < wid; k++) woff += wsum[k];
  int p = nbase + rs + woff + inc - v;  // exclusive prefix
  __syncthreads();
  lcnt[t] = p;
  // publish node-level offsets (keys with range==0)
  if (R == 4) {
    if ((t & 3) == 0) {
      int node = node_lo + (t >> 2);
      if (node < node_hi) nodeoff[node] = p;
    }
  } else {
    if ((t & 1) == 0) {
      int node = node_lo + (t >> 1);
      if (node < node_hi) nodeoff[node] = p;
    }
  }
  if (t == 0) nodeoff[node_hi] = nbase + re;  // benign same-value race with next bucket
  __syncthreads();
  // scatter (rec chunk L2-hot)
  for (int r = rs + t; r < re; r += 1024) {
    unsigned q = rec[r];
    int pp = atomicAdd(&lcnt[q >> 17], 1);
    nbr[pp] = (int)(q & 0x1FFFFu);
  }
}

// ---------- fused feature prep: user-emb f32->f16 | movie init | weight pack ----------
#define PREP_U 6250    // NU*64/4/256
#define PREP_M 12500   // (NM+3)/4
__global__ void __launch_bounds__(256)
k_prep(const float4* __restrict__ uemb4, unsigned short* __restrict__ uemb_h,
       const float* __restrict__ movie_x, const float* __restrict__ lin_W,
       const float* __restrict__ lin_b, const float* __restrict__ movie_emb,
       unsigned short* __restrict__ x_movie,
       const float* __restrict__ Wl0, const float* __restrict__ Wr0,
       const float* __restrict__ Wl1, const float* __restrict__ Wr1,
       const float* __restrict__ Wl2, const float* __restrict__ Wr2,
       const float* __restrict__ Wl3, const float* __restrict__ Wr3,
       unsigned short* __restrict__ Wc) {
  __shared__ float lwT[20 * 65];
  int b = blockIdx.x;
  if (b < PREP_U) {
    int i = b * 256 + threadIdx.x;  // < NU*16
    float4 v = uemb4[i];
    uint2 o;
    o.x = pk2h(v.x, v.y);
    o.y = pk2h(v.z, v.w);
    *(uint2*)(uemb_h + (size_t)i * 4) = o;
  } else if (b < PREP_U + PREP_M) {
    int bb = b - PREP_U;
    for (int gidx = threadIdx.x; gidx < 64 * 20; gidx += 256) {
      int h = gidx / 20;
      int f = gidx - h * 20;
      lwT[f * 65 + h] = lin_W[gidx];
    }
    __syncthreads();
    int w = (bb * 256 + (int)threadIdx.x) >> 6;
    int h = threadIdx.x & 63;
    if (w >= NM) return;
    float acc = lin_b[h] + movie_emb[(size_t)w * 64 + h];
    const float* mx = movie_x + (size_t)w * 20;
    #pragma unroll
    for (int f = 0; f < 20; f++) acc += mx[f] * lwT[f * 65 + h];
    x_movie[(size_t)w * 64 + h] = __builtin_bit_cast(unsigned short, (__half)__float2half(acc));
  } else {
    int wb = b - PREP_U - PREP_M;  // 0..127
    int which = wb >> 5;
    const float* Wl = which == 0 ? Wl0 : which == 1 ? Wl1 : which == 2 ? Wl2 : Wl3;
    const float* Wr = which == 0 ? Wr0 : which == 1 ? Wr1 : which == 2 ? Wr2 : Wr3;
    int i = (wb & 31) * 256 + threadIdx.x;
    if (i >= 8192) return;
    int h = i >> 7, k = i & 127;
    float v = (k < 64) ? Wl[h * 64 + k] : Wr[h * 64 + (k - 64)];
    Wc[which * 8192 + i] = __builtin_bit_cast(unsigned short, (__half)__float2half(v));
  }
}

// ---------- mean-gather, both relations in one dispatch ----------
// 1024-thread blocks (VGPR=20, no LDS -> 32 waves/CU vs 75% occupancy at
// 256). Tail: chunk-count-exact loads (no clamped duplicate rows) and
// hadd2 for fully-covered chunks -- only the boundary chunk pays the mask.
__global__ void __launch_bounds__(1024)
k_gmean2(const unsigned short* __restrict__ xsrcM,
         const unsigned short* __restrict__ xsrcU,
         const int* __restrict__ nbr,
         const int* __restrict__ nodeoffM, const int* __restrict__ nodeoffU,
         unsigned short* __restrict__ meanM, unsigned short* __restrict__ meanU) {
  int gw = (blockIdx.x * blockDim.x + threadIdx.x) >> 6;
  int lane = threadIdx.x & 63;
  if (gw >= NM + NU) return;  // wave-uniform
  bool mv = gw < NM;
  const char* xb = (const char*)(mv ? xsrcM : xsrcU);
  const int* noff = mv ? nodeoffM : nodeoffU;
  int w = mv ? gw : gw - NM;
  unsigned short* meanT = mv ? meanM : meanU;
  int g = lane >> 3;
  unsigned ib = (unsigned)(lane & 7) * 16;  // byte sub-offset within 128B row
  __half2 aa2[4];
  #pragma unroll
  for (int k = 0; k < 4; k++) aa2[k] = u2h2(0u);

  int s0 = noff[w], eN = noff[w + 1];
  int deg = eN - s0;
  int base = s0;

  #define ADD4(dd)                                   \
    aa2[0] = __hadd2(aa2[0], u2h2(dd.x));            \
    aa2[1] = __hadd2(aa2[1], u2h2(dd.y));            \
    aa2[2] = __hadd2(aa2[2], u2h2(dd.z));            \
    aa2[3] = __hadd2(aa2[3], u2h2(dd.w));
  #define CONSUME(dd, c, rr)                                            \
    {                                                                   \
      unsigned mcu = ((c) * 8 + g < (rr)) ? 0x3C003C00u : 0u;           \
      __half2 mc2 = u2h2(mcu);                                          \
      aa2[0] = __hfma2(u2h2(dd.x), mc2, aa2[0]);                        \
      aa2[1] = __hfma2(u2h2(dd.y), mc2, aa2[1]);                        \
      aa2[2] = __hfma2(u2h2(dd.z), mc2, aa2[2]);                        \
      aa2[3] = __hfma2(u2h2(dd.w), mc2, aa2[3]);                        \
    }

  // full 32-row windows: no clamps, no masks
  for (int nf = deg >> 5; nf > 0; nf--, base += 32) {
    int my = nbr[base + (lane & 31)];
    int j0 = __shfl(my, 0 * 8 + g);
    int j1 = __shfl(my, 1 * 8 + g);
    int j2 = __shfl(my, 2 * 8 + g);
    int j3 = __shfl(my, 3 * 8 + g);
    uint4 d0 = *(const uint4*)(xb + ((unsigned)(j0 << 7) + ib));
    uint4 d1 = *(const uint4*)(xb + ((unsigned)(j1 << 7) + ib));
    uint4 d2 = *(const uint4*)(xb + ((unsigned)(j2 << 7) + ib));
    uint4 d3 = *(const uint4*)(xb + ((unsigned)(j3 << 7) + ib));
    ADD4(d0) ADD4(d1) ADD4(d2) ADD4(d3)
  }
  // tail window (rem in [1,31]): load only needed chunks; mask only boundary
  int rem = eN - base;
  if (rem > 0) {
    int lim = rem - 1;
    int my = nbr[base + (lane < rem ? lane : 0)];
    int nc = (rem + 7) >> 3;  // 1..4 chunks (wave-uniform)
    uint4 d0, d1, d2, d3;
    {
      int j0 = __shfl(my, min(g, lim));
      d0 = *(const uint4*)(xb + ((unsigned)(j0 << 7) + ib));
    }
    if (nc > 1) {
      int j1 = __shfl(my, min(8 + g, lim));
      d1 = *(const uint4*)(xb + ((unsigned)(j1 << 7) + ib));
    }
    if (nc > 2) {
      int j2 = __shfl(my, min(16 + g, lim));
      d2 = *(const uint4*)(xb + ((unsigned)(j2 << 7) + ib));
    }
    if (nc > 3) {
      int j3 = __shfl(my, min(24 + g, lim));
      d3 = *(const uint4*)(xb + ((unsigned)(j3 << 7) + ib));
    }
    if (rem >= 8) { ADD4(d0) } else { CONSUME(d0, 0, rem) }
    if (nc > 1) {
      if (rem >= 16) { ADD4(d1) } else { CONSUME(d1, 1, rem) }
    }
    if (nc > 2) {
      if (rem >= 24) { ADD4(d2) } else { CONSUME(d2, 2, rem) }
    }
    if (nc > 3) {
      CONSUME(d3, 3, rem)  // rem < 32 always in tail
    }
  }
  #undef ADD4
  #undef CONSUME

  // cross-row-slot reduce over g (lane bits 3..5), packed adds
  #pragma unroll
  for (int m = 8; m <= 32; m <<= 1) {
    #pragma unroll
    for (int k = 0; k < 4; k++) aa2[k] = __hadd2(aa2[k], shfl_xor_h2(aa2[k], m));
  }
  float inv = 1.0f / fmaxf((float)deg, 1.0f);
  if (g == 0) {
    __half2 invh = __float2half2_rn(inv);
    uint4 o;
    o.x = __builtin_bit_cast(unsigned, __hmul2(aa2[0], invh));
    o.y = __builtin_bit_cast(unsigned, __hmul2(aa2[1], invh));
    o.z = __builtin_bit_cast(unsigned, __hmul2(aa2[2], invh));
    o.w = __builtin_bit_cast(unsigned, __hmul2(aa2[3], invh));
    *(uint4*)((char*)meanT + ((unsigned)(w << 7) + ib)) = o;
  }
}

// ---------- SAGE transform as f16 MFMA GEMM, both relations in one dispatch ----------
template <int RELU>
__global__ void __launch_bounds__(256)
k_sage_gemm2(const unsigned short* __restrict__ meanM, const unsigned short* __restrict__ dvM,
             const unsigned short* __restrict__ WcM, const float* __restrict__ biasM,
             unsigned short* __restrict__ outM,
             const unsigned short* __restrict__ meanU, const unsigned short* __restrict__ dvU,
             const unsigned short* __restrict__ WcU, const float* __restrict__ biasU,
             unsigned short* __restrict__ outU) {
  __shared__ float ot[4][16][68];
  const int tM = NM / 16, tU = NU / 16;
  int wv4 = threadIdx.x >> 6;
  int wvg = (blockIdx.x * blockDim.x + threadIdx.x) >> 6;
  int lane = threadIdx.x & 63;
  bool active = wvg < tM + tU;
  bool mv = wvg < tM;
  const unsigned short* meanT = mv ? meanM : meanU;
  const unsigned short* dvT = mv ? dvM : dvU;
  const unsigned short* Wc = mv ? WcM : WcU;
  const float* bias = mv ? biasM : biasU;
  unsigned short* outT = mv ? outM : outU;
  int n0 = (mv ? wvg : wvg - tM) * 16;
  int rr = lane & 15;
  int ks = lane >> 4;

  if (active) {
    f16x8 bf[4][4];
    #pragma unroll
    for (int t = 0; t < 4; t++)
      #pragma unroll
      for (int kk = 0; kk < 4; kk++)
        bf[t][kk] = *(const f16x8*)((const char*)Wc + (unsigned)(((t * 16 + rr) << 8) + kk * 64 + ks * 16));
    f32x4 acc[4];
    #pragma unroll
    for (int t = 0; t < 4; t++) {
      float b = bias[t * 16 + rr];
      acc[t] = (f32x4){b, b, b, b};
    }
    const char* am = (const char*)meanT + (unsigned)((n0 + rr) << 7);
    const char* ad = (const char*)dvT + (unsigned)((n0 + rr) << 7);
    f16x8 af[4];
    af[0] = *(const f16x8*)(am + ks * 16);
    af[1] = *(const f16x8*)(am + 64 + ks * 16);
    af[2] = *(const f16x8*)(ad + ks * 16);
    af[3] = *(const f16x8*)(ad + 64 + ks * 16);
    #pragma unroll
    for (int kk = 0; kk < 4; kk++)
      #pragma unroll
      for (int t = 0; t < 4; t++)
        acc[t] = __builtin_amdgcn_mfma_f32_16x16x32_f16(af[kk], bf[t][kk], acc[t], 0, 0, 0);
    #pragma unroll
    for (int t = 0; t < 4; t++)
      #pragma unroll
      for (int r = 0; r < 4; r++) {
        float v = acc[t][r];
        if (RELU) v = fmaxf(v, 0.f);
        ot[wv4][(lane >> 4) * 4 + r][t * 16 + rr] = v;
      }
  }
  __syncthreads();
  if (active) {
    int nn = lane >> 2, c4 = lane & 3;
    const float* src = &ot[wv4][nn][c4 * 16];
    uint4 o0, o1;
    o0.x = pk2h(src[0], src[1]);  o0.y = pk2h(src[2], src[3]);
    o0.z = pk2h(src[4], src[5]);  o0.w = pk2h(src[6], src[7]);
    o1.x = pk2h(src[8], src[9]);  o1.y = pk2h(src[10], src[11]);
    o1.z = pk2h(src[12], src[13]); o1.w = pk2h(src[14], src[15]);
    unsigned short* dst = outT + ((size_t)(n0 + nn) << 6) + c4 * 16;
    *(uint4*)dst = o0;
    *(uint4*)(dst + 8) = o1;
  }
}

// 8 lanes per edge on f16 rows (one uint4 = 16B/lane, 128B/row), shfl_xor
// reduce within 8-lane group. 32 edges per 256-thread block.
__global__ void __launch_bounds__(256)
k_dot(const unsigned short* __restrict__ u2, const unsigned short* __restrict__ m2,
      const int* __restrict__ eu, const int* __restrict__ em,
      float* __restrict__ out, int L) {
  int wave = (blockIdx.x * blockDim.x + threadIdx.x) >> 6;
  int lane = threadIdx.x & 63;
  int sub = lane & 7;
  int l = wave * 8 + (lane >> 3);
  int lc = l < L ? l : (L - 1);
  int iu = eu[lc], im = em[lc];
  uint4 a = *(const uint4*)((const char*)u2 + ((unsigned)(iu << 7) + sub * 16));
  uint4 b = *(const uint4*)((const char*)m2 + ((unsigned)(im << 7) + sub * 16));
  float2 a0 = __half22float2(u2h2(a.x)), b0 = __half22float2(u2h2(b.x));
  float2 a1 = __half22float2(u2h2(a.y)), b1 = __half22float2(u2h2(b.y));
  float2 a2 = __half22float2(u2h2(a.z)), b2 = __half22float2(u2h2(b.z));
  float2 a3 = __half22float2(u2h2(a.w)), b3 = __half22float2(u2h2(b.w));
  float s = a0.x * b0.x + a0.y * b0.y + a1.x * b1.x + a1.y * b1.y
          + a2.x * b2.x + a2.y * b2.y + a3.x * b3.x + a3.y * b3.y;
  s += __shfl_xor(s, 1);
  s += __shfl_xor(s, 2);
  s += __shfl_xor(s, 4);
  if (sub == 0 && l < L) out[l] = s;
}

extern "C" void kernel_launch(void* const* d_in, const int* in_sizes, int n_in,
                              void* d_out, int out_size, void* d_ws, size_t ws_size,
                              hipStream_t stream) {
  const float* movie_x   = (const float*)d_in[2];
  const int*   esrc      = (const int*)d_in[3];
  const int*   edst      = (const int*)d_in[4];
  const int*   eli_u     = (const int*)d_in[5];
  const int*   eli_m     = (const int*)d_in[6];
  const float* user_emb  = (const float*)d_in[7];
  const float* movie_emb = (const float*)d_in[8];
  const float* lin_W     = (const float*)d_in[9];
  const float* lin_b     = (const float*)d_in[10];
  const float* W1um_l = (const float*)d_in[11];
  const float* W1um_r = (const float*)d_in[12];
  const float* W1mu_l = (const float*)d_in[13];
  const float* W1mu_r = (const float*)d_in[14];
  const float* W2um_l = (const float*)d_in[15];
  const float* W2um_r = (const float*)d_in[16];
  const float* W2mu_l = (const float*)d_in[17];
  const float* W2mu_r = (const float*)d_in[18];
  const float* b1um = (const float*)d_in[19];
  const float* b1mu = (const float*)d_in[20];
  const float* b2um = (const float*)d_in[21];
  const float* b2mu = (const float*)d_in[22];
  const int E = in_sizes[3];
  const int L = in_sizes[5];

  char* ws = (char*)d_ws;
  size_t o = 0;
  auto alloc = [&](size_t bytes) -> void* {
    void* p = ws + o;
    o = (o + bytes + 255) & ~(size_t)255;
    return p;
  };
  unsigned short* uemb_h   = (unsigned short*)alloc((size_t)NU * 64 * 2);
  unsigned short* xmovie_h = (unsigned short*)alloc((size_t)NM * 64 * 2);
  unsigned short* m1_h     = (unsigned short*)alloc((size_t)NM * 64 * 2);
  unsigned short* u1_h     = (unsigned short*)alloc((size_t)NU * 64 * 2);
  unsigned short* m2_h     = (unsigned short*)alloc((size_t)NM * 64 * 2);
  unsigned short* u2_h     = (unsigned short*)alloc((size_t)NU * 64 * 2);
  unsigned short* mean_m   = (unsigned short*)alloc((size_t)NM * 64 * 2);
  unsigned short* mean_u   = (unsigned short*)alloc((size_t)NU * 64 * 2);
  unsigned short* wcat     = (unsigned short*)alloc(4 * 8192 * 2);
  int* nodeoffM = (int*)alloc((size_t)(NM + 1) * 4);
  int* nodeoffU = (int*)alloc((size_t)(NU + 1) * 4);
  int* bs    = (int*)alloc(4096);
  int* nbr   = (int*)alloc((size_t)2 * E * 4);
  int* hmat  = (int*)alloc((size_t)(2 * NH + 1) * 4);
  int* hbase = (int*)alloc((size_t)(2 * NH + 1) * 4);
  // rec buffers (E x 4B = 10MB each) overlay dead table regions during build.
  unsigned* rec_m = (unsigned*)uemb_h;
  unsigned* rec_u = (unsigned*)u1_h;

  // ===== merged CSR build =====
  k_hist2<<<NBLK, 1024, 0, stream>>>(esrc, edst, hmat, E);
  {
    int n = 2 * NH, nb = (n + 1023) / 1024;
    k_scan_part<<<nb, 256, 0, stream>>>(hmat, hbase, bs, n);
    k_scan_top<<<1, 64, 0, stream>>>(bs, nb);
    k_scan_add<<<(n + 1 + 255) / 256, 256, 0, stream>>>(hbase, bs, n, 2 * E);
  }
  k_part2<<<NBLK, 1024, 0, stream>>>(esrc, edst, hbase, rec_m, rec_u, E);
  k_bcsr<<<2 * NBKT, 1024, 0, stream>>>(rec_m, rec_u, hbase, nbr, nodeoffM, nodeoffU, E);

  // ===== fused feature prep (rec overlays now dead) =====
  k_prep<<<PREP_U + PREP_M + 128, 256, 0, stream>>>(
      (const float4*)user_emb, uemb_h, movie_x, lin_W, lin_b, movie_emb, xmovie_h,
      W1um_l, W1um_r, W1mu_l, W1mu_r, W2um_l, W2um_r, W2mu_l, W2mu_r, wcat);
  unsigned short* wc1um = wcat;
  unsigned short* wc1mu = wcat + 8192;
  unsigned short* wc2um = wcat + 16384;
  unsigned short* wc2mu = wcat + 24576;

  int gGm = (NM + NU + 15) / 16;  // 1024-thread blocks, 16 waves each
  int gG = ((NM / 16 + NU / 16) + 3) / 4;
  // layer 1
  k_gmean2<<<gGm, 1024, 0, stream>>>(uemb_h, xmovie_h, nbr, nodeoffM, nodeoffU, mean_m, mean_u);
  k_sage_gemm2<1><<<gG, 256, 0, stream>>>(mean_m, xmovie_h, wc1um, b1um, m1_h,
                                          mean_u, uemb_h, wc1mu, b1mu, u1_h);
  // layer 2
  k_gmean2<<<gGm, 1024, 0, stream>>>(u1_h, m1_h, nbr, nodeoffM, nodeoffU, mean_m, mean_u);
  k_sage_gemm2<0><<<gG, 256, 0, stream>>>(mean_m, m1_h, wc2um, b2um, m2_h,
                                          mean_u, u1_h, wc2mu, b2mu, u2_h);

  // 32 edges per 256-thread block
  k_dot<<<(L + 31) / 32, 256, 0, stream>>>(u2_h, m2_h, eli_u, eli_m, (float*)d_out, L);
}

// Round 18
// 313.701 us; speedup vs baseline: 1.0470x; 1.0470x over previous
//
#include <hip/hip_runtime.h>
#include <hip/hip_fp16.h>

#define NU 100000
#define NM 50000
#define RM 4      // user-table sub-ranges (movie-dest gather source)
#define RU 2      // movie-table sub-ranges (user-dest gather source)
#define NBLK 256  // partition blocks
#define NBKT 196  // coarse buckets (50000>>8 -> 196, 100000>>9 -> 196)
#define NH (NBKT * NBLK)

typedef __attribute__((ext_vector_type(8))) _Float16 f16x8;
typedef __attribute__((ext_vector_type(4))) float f32x4;

__device__ __forceinline__ unsigned pk2h(float a, float b) {
  return __builtin_bit_cast(unsigned, __floats2half2_rn(a, b));
}
__device__ __forceinline__ __half2 shfl_xor_h2(__half2 v, int m) {
  return __builtin_bit_cast(__half2, __shfl_xor(__builtin_bit_cast(int, v), m));
}
__device__ __forceinline__ __half2 u2h2(unsigned v) {
  return __builtin_bit_cast(__half2, v);
}

// ---------- scan machinery (for the coarse hist matrix only) ----------
__global__ void k_scan_part(const int* __restrict__ cnt, int* __restrict__ off,
                            int* __restrict__ bsum, int n) {
  __shared__ int wsum[4];
  int t = threadIdx.x;
  int base = blockIdx.x * 1024 + t * 4;
  int v0 = (base + 0 < n) ? cnt[base + 0] : 0;
  int v1 = (base + 1 < n) ? cnt[base + 1] : 0;
  int v2 = (base + 2 < n) ? cnt[base + 2] : 0;
  int v3 = (base + 3 < n) ? cnt[base + 3] : 0;
  int s = v0 + v1 + v2 + v3;
  int lane = t & 63;
  int inc = s;
  #pragma unroll
  for (int d = 1; d < 64; d <<= 1) {
    int x = __shfl_up(inc, d);
    if (lane >= d) inc += x;
  }
  int wid = t >> 6;
  if (lane == 63) wsum[wid] = inc;
  __syncthreads();
  int woff = 0;
  for (int i = 0; i < wid; i++) woff += wsum[i];
  int excl = woff + inc - s;
  if (base + 0 < n) off[base + 0] = excl;
  if (base + 1 < n) off[base + 1] = excl + v0;
  if (base + 2 < n) off[base + 2] = excl + v0 + v1;
  if (base + 3 < n) off[base + 3] = excl + v0 + v1 + v2;
  if (t == 255) bsum[blockIdx.x] = woff + inc;
}

__global__ void k_scan_top(int* bsum, int nb) {
  int lane = threadIdx.x;
  int carry = 0;
  for (int base = 0; base < nb; base += 64) {
    int i = base + lane;
    int v = (i < nb) ? bsum[i] : 0;
    int inc = v;
    #pragma unroll
    for (int d = 1; d < 64; d <<= 1) {
      int x = __shfl_up(inc, d);
      if (lane >= d) inc += x;
    }
    if (i < nb) bsum[i] = carry + inc - v;
    carry += __shfl(inc, 63);
  }
}

__global__ void k_scan_add(int* __restrict__ off, const int* __restrict__ bsum,
                           int n, int total) {
  int i = blockIdx.x * blockDim.x + threadIdx.x;
  if (i < n) {
    off[i] = off[i] + bsum[i >> 10];
  } else if (i == n) {
    off[n] = total;
  }
}

// ---------- merged radix-partition build (both CSRs per pass) ----------
__global__ void __launch_bounds__(1024)
k_hist2(const int* __restrict__ esrc, const int* __restrict__ edst,
        int* __restrict__ hmat, int E) {
  __shared__ int hm[NBKT], hu[NBKT];
  int t = threadIdx.x;
  for (int b = t; b < NBKT; b += 1024) { hm[b] = 0; hu[b] = 0; }
  __syncthreads();
  int chunk = (E + NBLK - 1) / NBLK;
  int beg = blockIdx.x * chunk;
  int end = min(beg + chunk, E);
  for (int e = beg + t; e < end; e += 1024) {
    atomicAdd(&hm[edst[e] >> 8], 1);
    atomicAdd(&hu[esrc[e] >> 9], 1);
  }
  __syncthreads();
  for (int b = t; b < NBKT; b += 1024) {
    hmat[b * NBLK + blockIdx.x] = hm[b];
    hmat[NH + b * NBLK + blockIdx.x] = hu[b];
  }
}

// 4B packed records: (lkey << 17) | payload
__global__ void __launch_bounds__(1024)
k_part2(const int* __restrict__ esrc, const int* __restrict__ edst,
        const int* __restrict__ hbase, unsigned* __restrict__ rec_m,
        unsigned* __restrict__ rec_u, int E) {
  __shared__ int cm[NBKT], cu[NBKT];
  int t = threadIdx.x;
  for (int b = t; b < NBKT; b += 1024) {
    cm[b] = hbase[b * NBLK + blockIdx.x];
    cu[b] = hbase[NH + b * NBLK + blockIdx.x] - E;
  }
  __syncthreads();
  int chunk = (E + NBLK - 1) / NBLK;
  int beg = blockIdx.x * chunk;
  int end = min(beg + chunk, E);
  for (int e = beg + t; e < end; e += 1024) {
    int d = edst[e], s = esrc[e];
    unsigned lm = (unsigned)(d & 255) * RM + (unsigned)s / 25000u;
    int pm = atomicAdd(&cm[d >> 8], 1);
    rec_m[pm] = (lm << 17) | (unsigned)s;
    unsigned lu = (unsigned)(s & 511) * RU + (unsigned)d / 25000u;
    int pu = atomicAdd(&cu[s >> 9], 1);
    rec_u[pu] = (lu << 17) | (unsigned)d;
  }
}

// Merged count + LOCAL scan + scatter (see round 14). 1024 threads: the
// in-LDS scan is exactly 1 element/thread (wlen == 1024 for both halves).
__global__ void __launch_bounds__(1024)
k_bcsr(const unsigned* __restrict__ rec_m, const unsigned* __restrict__ rec_u,
       const int* __restrict__ hbase, int* __restrict__ nbr,
       int* __restrict__ nodeoffM, int* __restrict__ nodeoffU, int E) {
  __shared__ int lcnt[1024];
  __shared__ int wsum[16];
  int b = blockIdx.x, t = threadIdx.x;
  bool mv = b < NBKT;
  int bb = mv ? b : b - NBKT;
  const unsigned* rec = mv ? rec_m : rec_u;
  int R = mv ? RM : RU, SH = mv ? 8 : 9, N = mv ? NM : NU;
  int* nodeoff = mv ? nodeoffM : nodeoffU;
  int rs = mv ? hbase[bb * NBLK] : hbase[NH + bb * NBLK] - E;
  int re = mv ? hbase[(bb + 1) * NBLK] : hbase[NH + (bb + 1) * NBLK] - E;
  int nbase = mv ? 0 : E;  // nbr region offset for this half
  int node_lo = bb << SH;
  int node_hi = min(node_lo + (1 << SH), N);
  lcnt[t] = 0;
  __syncthreads();
  for (int r = rs + t; r < re; r += 1024)
    atomicAdd(&lcnt[rec[r] >> 17], 1);
  __syncthreads();
  // block-wide exclusive scan of lcnt (1 elem/thread), rebased to nbase+rs
  int v = lcnt[t];
  int lane = t & 63;
  int inc = v;
  #pragma unroll
  for (int d = 1; d < 64; d <<= 1) {
    int x = __shfl_up(inc, d);
    if (lane >= d) inc += x;
  }
  int wid = t >> 6;
  if (lane == 63) wsum[wid] = inc;
  __syncthreads();
  int woff = 0;
  for (int k = 0; k < wid; k++) woff += wsum[k];
  int p = nbase + rs + woff + inc - v;  // exclusive prefix
  __syncthreads();
  lcnt[t] = p;
  // publish node-level offsets (keys with range==0)
  if (R == 4) {
    if ((t & 3) == 0) {
      int node = node_lo + (t >> 2);
      if (node < node_hi) nodeoff[node] = p;
    }
  } else {
    if ((t & 1) == 0) {
      int node = node_lo + (t >> 1);
      if (node < node_hi) nodeoff[node] = p;
    }
  }
  if (t == 0) nodeoff[node_hi] = nbase + re;  // benign same-value race with next bucket
  __syncthreads();
  // scatter (rec chunk L2-hot)
  for (int r = rs + t; r < re; r += 1024) {
    unsigned q = rec[r];
    int pp = atomicAdd(&lcnt[q >> 17], 1);
    nbr[pp] = (int)(q & 0x1FFFFu);
  }
}

// ---------- fused feature prep: user-emb f32->f16 | movie init | weight pack ----------
#define PREP_U 6250    // NU*64/4/256
#define PREP_M 12500   // (NM+3)/4
__global__ void __launch_bounds__(256)
k_prep(const float4* __restrict__ uemb4, unsigned short* __restrict__ uemb_h,
       const float* __restrict__ movie_x, const float* __restrict__ lin_W,
       const float* __restrict__ lin_b, const float* __restrict__ movie_emb,
       unsigned short* __restrict__ x_movie,
       const float* __restrict__ Wl0, const float* __restrict__ Wr0,
       const float* __restrict__ Wl1, const float* __restrict__ Wr1,
       const float* __restrict__ Wl2, const float* __restrict__ Wr2,
       const float* __restrict__ Wl3, const float* __restrict__ Wr3,
       unsigned short* __restrict__ Wc) {
  __shared__ float lwT[20 * 65];
  int b = blockIdx.x;
  if (b < PREP_U) {
    int i = b * 256 + threadIdx.x;  // < NU*16
    float4 v = uemb4[i];
    uint2 o;
    o.x = pk2h(v.x, v.y);
    o.y = pk2h(v.z, v.w);
    *(uint2*)(uemb_h + (size_t)i * 4) = o;
  } else if (b < PREP_U + PREP_M) {
    int bb = b - PREP_U;
    for (int gidx = threadIdx.x; gidx < 64 * 20; gidx += 256) {
      int h = gidx / 20;
      int f = gidx - h * 20;
      lwT[f * 65 + h] = lin_W[gidx];
    }
    __syncthreads();
    int w = (bb * 256 + (int)threadIdx.x) >> 6;
    int h = threadIdx.x & 63;
    if (w >= NM) return;
    float acc = lin_b[h] + movie_emb[(size_t)w * 64 + h];
    const float* mx = movie_x + (size_t)w * 20;
    #pragma unroll
    for (int f = 0; f < 20; f++) acc += mx[f] * lwT[f * 65 + h];
    x_movie[(size_t)w * 64 + h] = __builtin_bit_cast(unsigned short, (__half)__float2half(acc));
  } else {
    int wb = b - PREP_U - PREP_M;  // 0..127
    int which = wb >> 5;
    const float* Wl = which == 0 ? Wl0 : which == 1 ? Wl1 : which == 2 ? Wl2 : Wl3;
    const float* Wr = which == 0 ? Wr0 : which == 1 ? Wr1 : which == 2 ? Wr2 : Wr3;
    int i = (wb & 31) * 256 + threadIdx.x;
    if (i >= 8192) return;
    int h = i >> 7, k = i & 127;
    float v = (k < 64) ? Wl[h * 64 + k] : Wr[h * 64 + (k - 64)];
    Wc[which * 8192 + i] = __builtin_bit_cast(unsigned short, (__half)__float2half(v));
  }
}

// ---------- mean-gather, both relations in one dispatch ----------
// 256-thread blocks (round-17 post-mortem: 1024-thread blocks REGRESSED --
// 16-wave allocation granularity + deg-variance co-completion imbalance beat
// the nominal occupancy gain). Chunk-exact tail retained: load only
// (rem+7)/8 chunks; mask only the boundary chunk.
__global__ void __launch_bounds__(256)
k_gmean2(const unsigned short* __restrict__ xsrcM,
         const unsigned short* __restrict__ xsrcU,
         const int* __restrict__ nbr,
         const int* __restrict__ nodeoffM, const int* __restrict__ nodeoffU,
         unsigned short* __restrict__ meanM, unsigned short* __restrict__ meanU) {
  int gw = (blockIdx.x * blockDim.x + threadIdx.x) >> 6;
  int lane = threadIdx.x & 63;
  if (gw >= NM + NU) return;  // wave-uniform
  bool mv = gw < NM;
  const char* xb = (const char*)(mv ? xsrcM : xsrcU);
  const int* noff = mv ? nodeoffM : nodeoffU;
  int w = mv ? gw : gw - NM;
  unsigned short* meanT = mv ? meanM : meanU;
  int g = lane >> 3;
  unsigned ib = (unsigned)(lane & 7) * 16;  // byte sub-offset within 128B row
  __half2 aa2[4];
  #pragma unroll
  for (int k = 0; k < 4; k++) aa2[k] = u2h2(0u);

  int s0 = noff[w], eN = noff[w + 1];
  int deg = eN - s0;
  int base = s0;

  #define ADD4(dd)                                   \
    aa2[0] = __hadd2(aa2[0], u2h2(dd.x));            \
    aa2[1] = __hadd2(aa2[1], u2h2(dd.y));            \
    aa2[2] = __hadd2(aa2[2], u2h2(dd.z));            \
    aa2[3] = __hadd2(aa2[3], u2h2(dd.w));
  #define CONSUME(dd, c, rr)                                            \
    {                                                                   \
      unsigned mcu = ((c) * 8 + g < (rr)) ? 0x3C003C00u : 0u;           \
      __half2 mc2 = u2h2(mcu);                                          \
      aa2[0] = __hfma2(u2h2(dd.x), mc2, aa2[0]);                        \
      aa2[1] = __hfma2(u2h2(dd.y), mc2, aa2[1]);                        \
      aa2[2] = __hfma2(u2h2(dd.z), mc2, aa2[2]);                        \
      aa2[3] = __hfma2(u2h2(dd.w), mc2, aa2[3]);                        \
    }

  // full 32-row windows: no clamps, no masks
  for (int nf = deg >> 5; nf > 0; nf--, base += 32) {
    int my = nbr[base + (lane & 31)];
    int j0 = __shfl(my, 0 * 8 + g);
    int j1 = __shfl(my, 1 * 8 + g);
    int j2 = __shfl(my, 2 * 8 + g);
    int j3 = __shfl(my, 3 * 8 + g);
    uint4 d0 = *(const uint4*)(xb + ((unsigned)(j0 << 7) + ib));
    uint4 d1 = *(const uint4*)(xb + ((unsigned)(j1 << 7) + ib));
    uint4 d2 = *(const uint4*)(xb + ((unsigned)(j2 << 7) + ib));
    uint4 d3 = *(const uint4*)(xb + ((unsigned)(j3 << 7) + ib));
    ADD4(d0) ADD4(d1) ADD4(d2) ADD4(d3)
  }
  // tail window (rem in [1,31]): load only needed chunks; mask only boundary
  int rem = eN - base;
  if (rem > 0) {
    int lim = rem - 1;
    int my = nbr[base + (lane < rem ? lane : 0)];
    int nc = (rem + 7) >> 3;  // 1..4 chunks (wave-uniform)
    uint4 d0, d1, d2, d3;
    {
      int j0 = __shfl(my, min(g, lim));
      d0 = *(const uint4*)(xb + ((unsigned)(j0 << 7) + ib));
    }
    if (nc > 1) {
      int j1 = __shfl(my, min(8 + g, lim));
      d1 = *(const uint4*)(xb + ((unsigned)(j1 << 7) + ib));
    }
    if (nc > 2) {
      int j2 = __shfl(my, min(16 + g, lim));
      d2 = *(const uint4*)(xb + ((unsigned)(j2 << 7) + ib));
    }
    if (nc > 3) {
      int j3 = __shfl(my, min(24 + g, lim));
      d3 = *(const uint4*)(xb + ((unsigned)(j3 << 7) + ib));
    }
    if (rem >= 8) { ADD4(d0) } else { CONSUME(d0, 0, rem) }
    if (nc > 1) {
      if (rem >= 16) { ADD4(d1) } else { CONSUME(d1, 1, rem) }
    }
    if (nc > 2) {
      if (rem >= 24) { ADD4(d2) } else { CONSUME(d2, 2, rem) }
    }
    if (nc > 3) {
      CONSUME(d3, 3, rem)  // rem < 32 always in tail
    }
  }
  #undef ADD4
  #undef CONSUME

  // cross-row-slot reduce over g (lane bits 3..5), packed adds
  #pragma unroll
  for (int m = 8; m <= 32; m <<= 1) {
    #pragma unroll
    for (int k = 0; k < 4; k++) aa2[k] = __hadd2(aa2[k], shfl_xor_h2(aa2[k], m));
  }
  float inv = 1.0f / fmaxf((float)deg, 1.0f);
  if (g == 0) {
    __half2 invh = __float2half2_rn(inv);
    uint4 o;
    o.x = __builtin_bit_cast(unsigned, __hmul2(aa2[0], invh));
    o.y = __builtin_bit_cast(unsigned, __hmul2(aa2[1], invh));
    o.z = __builtin_bit_cast(unsigned, __hmul2(aa2[2], invh));
    o.w = __builtin_bit_cast(unsigned, __hmul2(aa2[3], invh));
    *(uint4*)((char*)meanT + ((unsigned)(w << 7) + ib)) = o;
  }
}

// ---------- SAGE transform as f16 MFMA GEMM, both relations in one dispatch ----------
template <int RELU>
__global__ void __launch_bounds__(256)
k_sage_gemm2(const unsigned short* __restrict__ meanM, const unsigned short* __restrict__ dvM,
             const unsigned short* __restrict__ WcM, const float* __restrict__ biasM,
             unsigned short* __restrict__ outM,
             const unsigned short* __restrict__ meanU, const unsigned short* __restrict__ dvU,
             const unsigned short* __restrict__ WcU, const float* __restrict__ biasU,
             unsigned short* __restrict__ outU) {
  __shared__ float ot[4][16][68];
  const int tM = NM / 16, tU = NU / 16;
  int wv4 = threadIdx.x >> 6;
  int wvg = (blockIdx.x * blockDim.x + threadIdx.x) >> 6;
  int lane = threadIdx.x & 63;
  bool active = wvg < tM + tU;
  bool mv = wvg < tM;
  const unsigned short* meanT = mv ? meanM : meanU;
  const unsigned short* dvT = mv ? dvM : dvU;
  const unsigned short* Wc = mv ? WcM : WcU;
  const float* bias = mv ? biasM : biasU;
  unsigned short* outT = mv ? outM : outU;
  int n0 = (mv ? wvg : wvg - tM) * 16;
  int rr = lane & 15;
  int ks = lane >> 4;

  if (active) {
    f16x8 bf[4][4];
    #pragma unroll
    for (int t = 0; t < 4; t++)
      #pragma unroll
      for (int kk = 0; kk < 4; kk++)
        bf[t][kk] = *(const f16x8*)((const char*)Wc + (unsigned)(((t * 16 + rr) << 8) + kk * 64 + ks * 16));
    f32x4 acc[4];
    #pragma unroll
    for (int t = 0; t < 4; t++) {
      float b = bias[t * 16 + rr];
      acc[t] = (f32x4){b, b, b, b};
    }
    const char* am = (const char*)meanT + (unsigned)((n0 + rr) << 7);
    const char* ad = (const char*)dvT + (unsigned)((n0 + rr) << 7);
    f16x8 af[4];
    af[0] = *(const f16x8*)(am + ks * 16);
    af[1] = *(const f16x8*)(am + 64 + ks * 16);
    af[2] = *(const f16x8*)(ad + ks * 16);
    af[3] = *(const f16x8*)(ad + 64 + ks * 16);
    #pragma unroll
    for (int kk = 0; kk < 4; kk++)
      #pragma unroll
      for (int t = 0; t < 4; t++)
        acc[t] = __builtin_amdgcn_mfma_f32_16x16x32_f16(af[kk], bf[t][kk], acc[t], 0, 0, 0);
    #pragma unroll
    for (int t = 0; t < 4; t++)
      #pragma unroll
      for (int r = 0; r < 4; r++) {
        float v = acc[t][r];
        if (RELU) v = fmaxf(v, 0.f);
        ot[wv4][(lane >> 4) * 4 + r][t * 16 + rr] = v;
      }
  }
  __syncthreads();
  if (active) {
    int nn = lane >> 2, c4 = lane & 3;
    const float* src = &ot[wv4][nn][c4 * 16];
    uint4 o0, o1;
    o0.x = pk2h(src[0], src[1]);  o0.y = pk2h(src[2], src[3]);
    o0.z = pk2h(src[4], src[5]);  o0.w = pk2h(src[6], src[7]);
    o1.x = pk2h(src[8], src[9]);  o1.y = pk2h(src[10], src[11]);
    o1.z = pk2h(src[12], src[13]); o1.w = pk2h(src[14], src[15]);
    unsigned short* dst = outT + ((size_t)(n0 + nn) << 6) + c4 * 16;
    *(uint4*)dst = o0;
    *(uint4*)(dst + 8) = o1;
  }
}

// 8 lanes per edge on f16 rows (one uint4 = 16B/lane, 128B/row), shfl_xor
// reduce within 8-lane group. 32 edges per 256-thread block.
__global__ void __launch_bounds__(256)
k_dot(const unsigned short* __restrict__ u2, const unsigned short* __restrict__ m2,
      const int* __restrict__ eu, const int* __restrict__ em,
      float* __restrict__ out, int L) {
  int wave = (blockIdx.x * blockDim.x + threadIdx.x) >> 6;
  int lane = threadIdx.x & 63;
  int sub = lane & 7;
  int l = wave * 8 + (lane >> 3);
  int lc = l < L ? l : (L - 1);
  int iu = eu[lc], im = em[lc];
  uint4 a = *(const uint4*)((const char*)u2 + ((unsigned)(iu << 7) + sub * 16));
  uint4 b = *(const uint4*)((const char*)m2 + ((unsigned)(im << 7) + sub * 16));
  float2 a0 = __half22float2(u2h2(a.x)), b0 = __half22float2(u2h2(b.x));
  float2 a1 = __half22float2(u2h2(a.y)), b1 = __half22float2(u2h2(b.y));
  float2 a2 = __half22float2(u2h2(a.z)), b2 = __half22float2(u2h2(b.z));
  float2 a3 = __half22float2(u2h2(a.w)), b3 = __half22float2(u2h2(b.w));
  float s = a0.x * b0.x + a0.y * b0.y + a1.x * b1.x + a1.y * b1.y
          + a2.x * b2.x + a2.y * b2.y + a3.x * b3.x + a3.y * b3.y;
  s += __shfl_xor(s, 1);
  s += __shfl_xor(s, 2);
  s += __shfl_xor(s, 4);
  if (sub == 0 && l < L) out[l] = s;
}

extern "C" void kernel_launch(void* const* d_in, const int* in_sizes, int n_in,
                              void* d_out, int out_size, void* d_ws, size_t ws_size,
                              hipStream_t stream) {
  const float* movie_x   = (const float*)d_in[2];
  const int*   esrc      = (const int*)d_in[3];
  const int*   edst      = (const int*)d_in[4];
  const int*   eli_u     = (const int*)d_in[5];
  const int*   eli_m     = (const int*)d_in[6];
  const float* user_emb  = (const float*)d_in[7];
  const float* movie_emb = (const float*)d_in[8];
  const float* lin_W     = (const float*)d_in[9];
  const float* lin_b     = (const float*)d_in[10];
  const float* W1um_l = (const float*)d_in[11];
  const float* W1um_r = (const float*)d_in[12];
  const float* W1mu_l = (const float*)d_in[13];
  const float* W1mu_r = (const float*)d_in[14];
  const float* W2um_l = (const float*)d_in[15];
  const float* W2um_r = (const float*)d_in[16];
  const float* W2mu_l = (const float*)d_in[17];
  const float* W2mu_r = (const float*)d_in[18];
  const float* b1um = (const float*)d_in[19];
  const float* b1mu = (const float*)d_in[20];
  const float* b2um = (const float*)d_in[21];
  const float* b2mu = (const float*)d_in[22];
  const int E = in_sizes[3];
  const int L = in_sizes[5];

  char* ws = (char*)d_ws;
  size_t o = 0;
  auto alloc = [&](size_t bytes) -> void* {
    void* p = ws + o;
    o = (o + bytes + 255) & ~(size_t)255;
    return p;
  };
  unsigned short* uemb_h   = (unsigned short*)alloc((size_t)NU * 64 * 2);
  unsigned short* xmovie_h = (unsigned short*)alloc((size_t)NM * 64 * 2);
  unsigned short* m1_h     = (unsigned short*)alloc((size_t)NM * 64 * 2);
  unsigned short* u1_h     = (unsigned short*)alloc((size_t)NU * 64 * 2);
  unsigned short* m2_h     = (unsigned short*)alloc((size_t)NM * 64 * 2);
  unsigned short* u2_h     = (unsigned short*)alloc((size_t)NU * 64 * 2);
  unsigned short* mean_m   = (unsigned short*)alloc((size_t)NM * 64 * 2);
  unsigned short* mean_u   = (unsigned short*)alloc((size_t)NU * 64 * 2);
  unsigned short* wcat     = (unsigned short*)alloc(4 * 8192 * 2);
  int* nodeoffM = (int*)alloc((size_t)(NM + 1) * 4);
  int* nodeoffU = (int*)alloc((size_t)(NU + 1) * 4);
  int* bs    = (int*)alloc(4096);
  int* nbr   = (int*)alloc((size_t)2 * E * 4);
  int* hmat  = (int*)alloc((size_t)(2 * NH + 1) * 4);
  int* hbase = (int*)alloc((size_t)(2 * NH + 1) * 4);
  // rec buffers (E x 4B = 10MB each) overlay dead table regions during build.
  unsigned* rec_m = (unsigned*)uemb_h;
  unsigned* rec_u = (unsigned*)u1_h;

  // ===== merged CSR build =====
  k_hist2<<<NBLK, 1024, 0, stream>>>(esrc, edst, hmat, E);
  {
    int n = 2 * NH, nb = (n + 1023) / 1024;
    k_scan_part<<<nb, 256, 0, stream>>>(hmat, hbase, bs, n);
    k_scan_top<<<1, 64, 0, stream>>>(bs, nb);
    k_scan_add<<<(n + 1 + 255) / 256, 256, 0, stream>>>(hbase, bs, n, 2 * E);
  }
  k_part2<<<NBLK, 1024, 0, stream>>>(esrc, edst, hbase, rec_m, rec_u, E);
  k_bcsr<<<2 * NBKT, 1024, 0, stream>>>(rec_m, rec_u, hbase, nbr, nodeoffM, nodeoffU, E);

  // ===== fused feature prep (rec overlays now dead) =====
  k_prep<<<PREP_U + PREP_M + 128, 256, 0, stream>>>(
      (const float4*)user_emb, uemb_h, movie_x, lin_W, lin_b, movie_emb, xmovie_h,
      W1um_l, W1um_r, W1mu_l, W1mu_r, W2um_l, W2um_r, W2mu_l, W2mu_r, wcat);
  unsigned short* wc1um = wcat;
  unsigned short* wc1mu = wcat + 8192;
  unsigned short* wc2um = wcat + 16384;
  unsigned short* wc2mu = wcat + 24576;

  int gGm = (NM + NU + 3) / 4;  // 256-thread blocks, 4 waves each
  int gG = ((NM / 16 + NU / 16) + 3) / 4;
  // layer 1
  k_gmean2<<<gGm, 256, 0, stream>>>(uemb_h, xmovie_h, nbr, nodeoffM, nodeoffU, mean_m, mean_u);
  k_sage_gemm2<1><<<gG, 256, 0, stream>>>(mean_m, xmovie_h, wc1um, b1um, m1_h,
                                          mean_u, uemb_h, wc1mu, b1mu, u1_h);
  // layer 2
  k_gmean2<<<gGm, 256, 0, stream>>>(u1_h, m1_h, nbr, nodeoffM, nodeoffU, mean_m, mean_u);
  k_sage_gemm2<0><<<gG, 256, 0, stream>>>(mean_m, m1_h, wc2um, b2um, m2_h,
                                          mean_u, u1_h, wc2mu, b2mu, u2_h);

  // 32 edges per 256-thread block
  k_dot<<<(L + 31) / 32, 256, 0, stream>>>(u2_h, m2_h, eli_u, eli_m, (float*)d_out, L);
}